// Round 2
// baseline (1899.168 us; speedup 1.0000x reference)
//
#include <hip/hip_runtime.h>

#define THREADS 512
#define LVLS 16
#define TSZ 524288u
#define TMASK 524287u
#define PRIME1 2654435761u
#define DIN 204
#define HID 64

constexpr float resf(int l) { double r = 16.0; for (int i = 0; i < l; ++i) r *= 1.3819; return (float)r; }

__device__ __constant__ float c_RES[LVLS] = {
    resf(0),  resf(1),  resf(2),  resf(3),
    resf(4),  resf(5),  resf(6),  resf(7),
    resf(8),  resf(9),  resf(10), resf(11),
    resf(12), resf(13), resf(14), resf(15)
};

struct Corners {
    float2 f00a, f10a, f01a, f11a;
    float2 f00b, f10b, f01b, f11b;
    float wxa, wya, wxb, wyb;
};

__device__ __forceinline__ void hash_load(const float2* __restrict__ tbase,
                                          float px, float py, int l,
                                          float2& f00, float2& f10,
                                          float2& f01, float2& f11,
                                          float& wx, float& wy)
{
    const float r = c_RES[l];
    const float fx = px * r, fy = py * r;
    const float flx = floorf(fx), fly = floorf(fy);
    wx = fx - flx;
    wy = fy - fly;
    const unsigned x0 = (unsigned)(int)flx;
    const unsigned y0 = (unsigned)(int)fly;
    const unsigned hy0 = y0 * PRIME1;
    const unsigned hy1 = (y0 + 1u) * PRIME1;
    const float2* tab = tbase + (size_t)l * TSZ;
    f00 = tab[(x0 ^ hy0) & TMASK];
    f10 = tab[((x0 + 1u) ^ hy0) & TMASK];
    f01 = tab[(x0 ^ hy1) & TMASK];
    f11 = tab[((x0 + 1u) ^ hy1) & TMASK];
}

__device__ __forceinline__ void load_pair(const float2* __restrict__ tbase,
                                          float px, float py, int p, Corners& C)
{
    hash_load(tbase, px, py, 2 * p,     C.f00a, C.f10a, C.f01a, C.f11a, C.wxa, C.wya);
    hash_load(tbase, px, py, 2 * p + 1, C.f00b, C.f10b, C.f01b, C.f11b, C.wxb, C.wyb);
}

// Fused rank-1 update for two levels (4 W1 rows) at once.
__device__ __forceinline__ void update_pair(const float* __restrict__ sW1, int s, int p,
                                            const Corners& C, float* __restrict__ h1)
{
    const float w00a = (1.f - C.wxa) * (1.f - C.wya);
    const float w10a = C.wxa * (1.f - C.wya);
    const float w01a = (1.f - C.wxa) * C.wya;
    const float w11a = C.wxa * C.wya;
    const float e0a = C.f00a.x * w00a + C.f10a.x * w10a + C.f01a.x * w01a + C.f11a.x * w11a;
    const float e1a = C.f00a.y * w00a + C.f10a.y * w10a + C.f01a.y * w01a + C.f11a.y * w11a;

    const float w00b = (1.f - C.wxb) * (1.f - C.wyb);
    const float w10b = C.wxb * (1.f - C.wyb);
    const float w01b = (1.f - C.wxb) * C.wyb;
    const float w11b = C.wxb * C.wyb;
    const float e0b = C.f00b.x * w00b + C.f10b.x * w10b + C.f01b.x * w01b + C.f11b.x * w11b;
    const float e1b = C.f00b.y * w00b + C.f10b.y * w10b + C.f01b.y * w01b + C.f11b.y * w11b;

    // enc columns for levels 2p, 2p+1 are rows s*34+4p .. s*34+4p+3 of W1.
    const float4* w0 = (const float4*)&sW1[(s * 34 + 4 * p) * HID];
    const float4* w1 = w0 + 16;
    const float4* w2 = w0 + 32;
    const float4* w3 = w0 + 48;
    #pragma unroll
    for (int q = 0; q < 16; ++q) {
        const float4 a = w0[q];
        const float4 b = w1[q];
        const float4 c = w2[q];
        const float4 d = w3[q];
        h1[4 * q + 0] += e0a * a.x + e1a * b.x + e0b * c.x + e1b * d.x;
        h1[4 * q + 1] += e0a * a.y + e1a * b.y + e0b * c.y + e1b * d.y;
        h1[4 * q + 2] += e0a * a.z + e1a * b.z + e0b * c.z + e1b * d.z;
        h1[4 * q + 3] += e0a * a.w + e1a * b.w + e0b * c.w + e1b * d.w;
    }
}

__global__ __launch_bounds__(THREADS, 3) void fused_hashmlp(
    const float* __restrict__ pxy, const float* __restrict__ pxz,
    const float* __restrict__ pyz, const float* __restrict__ pxt,
    const float* __restrict__ pyt, const float* __restrict__ pzt,
    const float* __restrict__ tables, const float* __restrict__ W1,
    const float* __restrict__ W2, const float* __restrict__ W3,
    float* __restrict__ out, int npts)
{
    __shared__ float sW1[DIN * HID];      // [204][64] row-major
    __shared__ float sW2T[HID * HID];     // transposed: [m][k]
    __shared__ float sW3[HID * 3];

    const int tid = threadIdx.x;
    for (int i = tid; i < DIN * HID / 4; i += THREADS)
        ((float4*)sW1)[i] = ((const float4*)W1)[i];
    for (int i = tid; i < HID * HID; i += THREADS)
        sW2T[(i & 63) * HID + (i >> 6)] = W2[i];
    for (int i = tid; i < HID * 3; i += THREADS)
        sW3[i] = W3[i];
    __syncthreads();

    const int gid = blockIdx.x * THREADS + tid;

    float h1[HID];
    #pragma unroll
    for (int k = 0; k < HID; ++k) h1[k] = 0.f;

    #pragma unroll 1
    for (int s = 0; s < 6; ++s) {
        float2 pt;
        switch (s) {  // wave-uniform branch
            case 0: pt = ((const float2*)pxy)[gid]; break;
            case 1: pt = ((const float2*)pxz)[gid]; break;
            case 2: pt = ((const float2*)pyz)[gid]; break;
            case 3: pt = ((const float2*)pxt)[gid]; break;
            case 4: pt = ((const float2*)pyt)[gid]; break;
            default: pt = ((const float2*)pzt)[gid]; break;
        }
        const float px = pt.x, py = pt.y;
        const float2* tbase = ((const float2*)tables) + (size_t)s * LVLS * TSZ;

        Corners A, B;
        load_pair(tbase, px, py, 0, A);
        #pragma unroll 1
        for (int p = 0; p < 6; p += 2) {
            load_pair(tbase, px, py, p + 1, B);   // prefetch next pair
            update_pair(sW1, s, p, A, h1);        // hides B's gathers
            load_pair(tbase, px, py, p + 2, A);   // prefetch next-next
            update_pair(sW1, s, p + 1, B, h1);    // hides A's gathers
        }
        load_pair(tbase, px, py, 7, B);
        update_pair(sW1, s, 6, A, h1);
        update_pair(sW1, s, 7, B, h1);

        // raw coords: columns s*34+32, s*34+33
        const float4* wc = (const float4*)&sW1[(s * 34 + 32) * HID];
        #pragma unroll
        for (int q = 0; q < 16; ++q) {
            const float4 a = wc[q];
            const float4 b = wc[16 + q];
            h1[4 * q + 0] += px * a.x + py * b.x;
            h1[4 * q + 1] += px * a.y + py * b.y;
            h1[4 * q + 2] += px * a.z + py * b.z;
            h1[4 * q + 3] += px * a.w + py * b.w;
        }
    }

    #pragma unroll
    for (int k = 0; k < HID; ++k) h1[k] = fmaxf(h1[k], 0.f);

    float o0 = 0.f, o1 = 0.f, o2 = 0.f;
    #pragma unroll 1
    for (int m = 0; m < HID; ++m) {
        const float4* wrow = (const float4*)&sW2T[m * HID];
        float t = 0.f;
        #pragma unroll
        for (int q = 0; q < 16; ++q) {
            const float4 a = wrow[q];
            t += h1[4 * q + 0] * a.x + h1[4 * q + 1] * a.y
               + h1[4 * q + 2] * a.z + h1[4 * q + 3] * a.w;
        }
        t = fmaxf(t, 0.f);
        o0 += t * sW3[3 * m + 0];
        o1 += t * sW3[3 * m + 1];
        o2 += t * sW3[3 * m + 2];
    }

    if (gid < npts) {
        out[3 * gid + 0] = o0;
        out[3 * gid + 1] = o1;
        out[3 * gid + 2] = o2;
    }
}

extern "C" void kernel_launch(void* const* d_in, const int* in_sizes, int n_in,
                              void* d_out, int out_size, void* d_ws, size_t ws_size,
                              hipStream_t stream)
{
    const float* pxy = (const float*)d_in[0];
    const float* pxz = (const float*)d_in[1];
    const float* pyz = (const float*)d_in[2];
    const float* pxt = (const float*)d_in[3];
    const float* pyt = (const float*)d_in[4];
    const float* pzt = (const float*)d_in[5];
    const float* tables = (const float*)d_in[6];
    const float* W1 = (const float*)d_in[7];
    const float* W2 = (const float*)d_in[8];
    const float* W3 = (const float*)d_in[9];
    float* out = (float*)d_out;

    const int npts = in_sizes[0] / 2;
    const int grid = (npts + THREADS - 1) / THREADS;

    hipLaunchKernelGGL(fused_hashmlp, dim3(grid), dim3(THREADS), 0, stream,
                       pxy, pxz, pyz, pxt, pyt, pzt, tables, W1, W2, W3, out, npts);
}

// Round 3
// 1722.300 us; speedup vs baseline: 1.1027x; 1.1027x over previous
//
#include <hip/hip_runtime.h>

#define THREADS 256
#define LVLS 16
#define TSZ 524288u
#define TMASK 524287u
#define PRIME1 2654435761u
#define HID 64

constexpr float resf(int l) { double r = 16.0; for (int i = 0; i < l; ++i) r *= 1.3819; return (float)r; }

__device__ __constant__ float c_RES[LVLS] = {
    resf(0),  resf(1),  resf(2),  resf(3),
    resf(4),  resf(5),  resf(6),  resf(7),
    resf(8),  resf(9),  resf(10), resf(11),
    resf(12), resf(13), resf(14), resf(15)
};

__global__ __launch_bounds__(THREADS, 4) void fused_hashmlp(
    const float* __restrict__ pxy, const float* __restrict__ pxz,
    const float* __restrict__ pyz, const float* __restrict__ pxt,
    const float* __restrict__ pyt, const float* __restrict__ pzt,
    const float* __restrict__ tables, const float* __restrict__ W1,
    const float* __restrict__ W2, const float* __restrict__ W3,
    float* __restrict__ out, int npts)
{
    const int gid = blockIdx.x * THREADS + threadIdx.x;

    float h1[HID];
    #pragma unroll
    for (int k = 0; k < HID; ++k) h1[k] = 0.f;

    #pragma unroll 1
    for (int s = 0; s < 6; ++s) {
        float2 pt;
        switch (s) {  // wave-uniform branch
            case 0: pt = ((const float2*)pxy)[gid]; break;
            case 1: pt = ((const float2*)pxz)[gid]; break;
            case 2: pt = ((const float2*)pyz)[gid]; break;
            case 3: pt = ((const float2*)pxt)[gid]; break;
            case 4: pt = ((const float2*)pyt)[gid]; break;
            default: pt = ((const float2*)pzt)[gid]; break;
        }
        const float px = pt.x, py = pt.y;
        const float2* tbase = ((const float2*)tables) + (size_t)s * LVLS * TSZ;
        const float* w1s = W1 + (s * 34) * HID;   // rows for this plane

        #pragma unroll 2
        for (int l = 0; l < LVLS; ++l) {
            const float r = c_RES[l];
            const float fx = px * r, fy = py * r;
            const float flx = floorf(fx), fly = floorf(fy);
            const float wx = fx - flx, wy = fy - fly;
            const unsigned x0 = (unsigned)(int)flx;
            const unsigned y0 = (unsigned)(int)fly;
            const unsigned hy0 = y0 * PRIME1;
            const unsigned hy1 = (y0 + 1u) * PRIME1;
            const float2* tab = tbase + (size_t)l * TSZ;

            const float2 f00 = tab[(x0 ^ hy0) & TMASK];
            const float2 f10 = tab[((x0 + 1u) ^ hy0) & TMASK];
            const float2 f01 = tab[(x0 ^ hy1) & TMASK];
            const float2 f11 = tab[((x0 + 1u) ^ hy1) & TMASK];

            const float w00 = (1.f - wx) * (1.f - wy);
            const float w10 = wx * (1.f - wy);
            const float w01 = (1.f - wx) * wy;
            const float w11 = wx * wy;
            const float e0 = f00.x * w00 + f10.x * w10 + f01.x * w01 + f11.x * w11;
            const float e1 = f00.y * w00 + f10.y * w10 + f01.y * w01 + f11.y * w11;

            // W1 rows 2l, 2l+1 of this plane — wave-uniform addresses -> s_load
            const float4* wa = (const float4*)(w1s + (2 * l) * HID);
            const float4* wb = wa + 16;
            #pragma unroll
            for (int q = 0; q < 16; ++q) {
                const float4 a = wa[q];
                const float4 b = wb[q];
                h1[4 * q + 0] += e0 * a.x + e1 * b.x;
                h1[4 * q + 1] += e0 * a.y + e1 * b.y;
                h1[4 * q + 2] += e0 * a.z + e1 * b.z;
                h1[4 * q + 3] += e0 * a.w + e1 * b.w;
            }
        }

        // raw coord rows s*34+32, s*34+33
        {
            const float4* wa = (const float4*)(w1s + 32 * HID);
            const float4* wb = wa + 16;
            #pragma unroll
            for (int q = 0; q < 16; ++q) {
                const float4 a = wa[q];
                const float4 b = wb[q];
                h1[4 * q + 0] += px * a.x + py * b.x;
                h1[4 * q + 1] += px * a.y + py * b.y;
                h1[4 * q + 2] += px * a.z + py * b.z;
                h1[4 * q + 3] += px * a.w + py * b.w;
            }
        }
    }

    #pragma unroll
    for (int k = 0; k < HID; ++k) h1[k] = fmaxf(h1[k], 0.f);

    float o0 = 0.f, o1 = 0.f, o2 = 0.f;
    #pragma unroll 1
    for (int c = 0; c < 4; ++c) {           // 16 output cols of W2 at a time
        float t[16];
        #pragma unroll
        for (int i = 0; i < 16; ++i) t[i] = 0.f;
        #pragma unroll
        for (int k = 0; k < HID; ++k) {
            const float4* w2r = (const float4*)(W2 + k * HID + c * 16);
            const float hk = h1[k];
            const float4 a = w2r[0];
            const float4 b = w2r[1];
            const float4 d = w2r[2];
            const float4 e = w2r[3];
            t[0]  += hk * a.x;  t[1]  += hk * a.y;  t[2]  += hk * a.z;  t[3]  += hk * a.w;
            t[4]  += hk * b.x;  t[5]  += hk * b.y;  t[6]  += hk * b.z;  t[7]  += hk * b.w;
            t[8]  += hk * d.x;  t[9]  += hk * d.y;  t[10] += hk * d.z;  t[11] += hk * d.w;
            t[12] += hk * e.x;  t[13] += hk * e.y;  t[14] += hk * e.z;  t[15] += hk * e.w;
        }
        #pragma unroll
        for (int i = 0; i < 16; ++i) {
            const float tt = fmaxf(t[i], 0.f);
            const int m = c * 16 + i;
            o0 += tt * W3[m * 3 + 0];
            o1 += tt * W3[m * 3 + 1];
            o2 += tt * W3[m * 3 + 2];
        }
    }

    if (gid < npts) {
        out[3 * gid + 0] = o0;
        out[3 * gid + 1] = o1;
        out[3 * gid + 2] = o2;
    }
}

extern "C" void kernel_launch(void* const* d_in, const int* in_sizes, int n_in,
                              void* d_out, int out_size, void* d_ws, size_t ws_size,
                              hipStream_t stream)
{
    const float* pxy = (const float*)d_in[0];
    const float* pxz = (const float*)d_in[1];
    const float* pyz = (const float*)d_in[2];
    const float* pxt = (const float*)d_in[3];
    const float* pyt = (const float*)d_in[4];
    const float* pzt = (const float*)d_in[5];
    const float* tables = (const float*)d_in[6];
    const float* W1 = (const float*)d_in[7];
    const float* W2 = (const float*)d_in[8];
    const float* W3 = (const float*)d_in[9];
    float* out = (float*)d_out;

    const int npts = in_sizes[0] / 2;
    const int grid = (npts + THREADS - 1) / THREADS;

    hipLaunchKernelGGL(fused_hashmlp, dim3(grid), dim3(THREADS), 0, stream,
                       pxy, pxz, pyz, pxt, pyt, pzt, tables, W1, W2, W3, out, npts);
}